// Round 7
// baseline (167.091 us; speedup 1.0000x reference)
//
#include <hip/hip_runtime.h>
#include <hip/hip_fp16.h>

#define NN 100000
#define EE 1600000
#define FF 128
#define CC 10
#define GG 256
#define PC 16        // padded channels
#define WSH 7        // rows per window = 128
#define NW 782       // ceil(NN / 128)
#define WCAP 2560    // records per window capacity (mean 2046, +11 sigma)
#define EPB 8192     // edges per partition block (196 blocks -> ~200 CUs busy)

// ---------- partition: sort 8K edges in LDS by window, write contiguous segments ----------

__global__ __launch_bounds__(1024) void partition_edges(
        const int* __restrict__ eidx, int* __restrict__ wfill,
        unsigned int* __restrict__ rec, int E) {
    __shared__ unsigned int srec[EPB];          // 32 KB
    __shared__ unsigned short sw[EPB];          // 16 KB
    __shared__ int lcnt[NW];
    __shared__ int lofs[NW];
    __shared__ int lcur[NW];
    __shared__ int lgb[NW];
    __shared__ int sscan[1024];
    const int tid = threadIdx.x;
    const int e0 = blockIdx.x * EPB;
    const int n = min(EPB, E - e0);

    for (int i = tid; i < NW; i += 1024) lcnt[i] = 0;
    __syncthreads();

    // load this thread's (up to) 8 edges into registers + histogram
    int rr[8], cc[8];
    #pragma unroll
    for (int k = 0; k < 8; ++k) {
        int i = tid + (k << 10);
        if (i < n) {
            rr[k] = eidx[e0 + i];
            cc[k] = eidx[EE + e0 + i];
            atomicAdd(&lcnt[rr[k] >> WSH], 1);
        }
    }
    __syncthreads();

    sscan[tid] = (tid < NW) ? lcnt[tid] : 0;
    __syncthreads();
    for (int s = 1; s < 1024; s <<= 1) {
        int t = 0;
        if (tid >= s) t = sscan[tid - s];
        __syncthreads();
        if (tid >= s) sscan[tid] += t;
        __syncthreads();
    }
    if (tid < NW) {
        int excl = sscan[tid] - lcnt[tid];
        lofs[tid] = excl;
        lcur[tid] = excl;
    }
    __syncthreads();

    // scatter into LDS sorted-by-window
    #pragma unroll
    for (int k = 0; k < 8; ++k) {
        int i = tid + (k << 10);
        if (i < n) {
            int w = rr[k] >> WSH;
            int p = atomicAdd(&lcur[w], 1);
            srec[p] = ((unsigned int)(rr[k] & 127) << 17) | (unsigned int)cc[k];
            sw[p] = (unsigned short)w;
        }
    }
    __syncthreads();

    // reserve global segments
    if (tid < NW) {
        int cw = lcnt[tid];
        lgb[tid] = cw ? atomicAdd(&wfill[tid], cw) : 0;
    }
    __syncthreads();

    // write contiguous runs
    for (int i = tid; i < n; i += 1024) {
        int w = sw[i];
        int pos = lgb[w] + (i - lofs[w]);
        if (pos < WCAP) rec[(size_t)w * WCAP + pos] = srec[i];
    }
}

// ---------- y0 = x @ W (quad per node), output packed fp16 [N][16] (32B rows) ----------

__global__ void xw_kernel(const float4* __restrict__ x4,   // [N][32]
                          const float* __restrict__ W,     // [128][10]
                          uint2* __restrict__ y0,          // [N][4] x 8B (fp16x4)
                          int N) {
    __shared__ float4 WT[CC][32];   // WT[c][k] = W[4k..4k+3][c]
    for (int i = threadIdx.x; i < CC * 32; i += blockDim.x) {
        int c = i >> 5, k = i & 31;
        WT[c][k] = make_float4(W[(4 * k + 0) * CC + c], W[(4 * k + 1) * CC + c],
                               W[(4 * k + 2) * CC + c], W[(4 * k + 3) * CC + c]);
    }
    __syncthreads();
    int node = blockIdx.x * 64 + (threadIdx.x >> 2);
    int lane = threadIdx.x & 3;
    if (node >= N) return;
    float a[CC];
    #pragma unroll
    for (int c = 0; c < CC; ++c) a[c] = 0.f;
    #pragma unroll
    for (int k = 0; k < 8; ++k) {
        float4 xv = x4[(size_t)node * 32 + k * 4 + lane];
        #pragma unroll
        for (int c = 0; c < CC; ++c) {
            float4 wv = WT[c][k * 4 + lane];
            a[c] += xv.x * wv.x + xv.y * wv.y + xv.z * wv.z + xv.w * wv.w;
        }
    }
    #pragma unroll
    for (int c = 0; c < CC; ++c) {
        a[c] += __shfl_xor(a[c], 1);
        a[c] += __shfl_xor(a[c], 2);
    }
    float4 o;
    if (lane == 0)      o = make_float4(a[0], a[1], a[2], a[3]);
    else if (lane == 1) o = make_float4(a[4], a[5], a[6], a[7]);
    else if (lane == 2) o = make_float4(a[8], a[9], 0.f, 0.f);
    else                o = make_float4(0.f, 0.f, 0.f, 0.f);
    __half2 h01 = __floats2half2_rn(o.x, o.y);
    __half2 h23 = __floats2half2_rn(o.z, o.w);
    uint2 pkd;
    pkd.x = *(unsigned int*)&h01;
    pkd.y = *(unsigned int*)&h23;
    y0[(size_t)node * 4 + lane] = pkd;
}

__device__ __forceinline__ void acc_half4(float4& acc, uint2 v) {
    __half2 h0 = *(__half2*)&v.x;
    __half2 h1 = *(__half2*)&v.y;
    float2 f0 = __half22float2(h0);
    float2 f1 = __half22float2(h1);
    acc.x += f0.x; acc.y += f0.y; acc.z += f1.x; acc.w += f1.y;
}

// ---------- window SpMM: local CSR in LDS, register accumulate per row ----------
// POOL=false: write fp16 dst rows.
// POOL=true: fuse per-graph pooling (sum + counts) and final output (ticket).

template<bool POOL>
__global__ __launch_bounds__(512) void window_spmm(
        const uint2* __restrict__ src,             // [N][4] fp16x4
        const unsigned int* __restrict__ rec,
        const int* __restrict__ wfill, const int* __restrict__ batch,
        uint2* __restrict__ dst, float* __restrict__ pooled,
        int* __restrict__ gcount, int* __restrict__ ticket,
        const float* __restrict__ bvec, float* __restrict__ out, int N) {
    __shared__ int cnt[128];
    __shared__ int sscan[128];
    __shared__ int rptr[129];
    __shared__ int cur[128];
    __shared__ int lcols[WCAP];        // 10 KB
    __shared__ float spool[32 * PC];
    __shared__ int spcnt[32];
    __shared__ int sbatch[128];
    __shared__ int is_last;

    const int tid = threadIdx.x;
    const int w = blockIdx.x;
    const int row0 = w << WSH;
    const int n = min(wfill[w], WCAP);
    const unsigned int* rp = rec + (size_t)w * WCAP;

    if (tid < 128) {
        cnt[tid] = 0;
        if (POOL) {
            int node = row0 + tid;
            sbatch[tid] = (node < N) ? batch[node] : -1;
        }
    }
    if (POOL) {
        for (int i = tid; i < 32 * PC; i += 512) spool[i] = 0.f;
        if (tid < 32) spcnt[tid] = 0;
    }
    __syncthreads();

    // histogram rows
    for (int i = tid; i < n; i += 512)
        atomicAdd(&cnt[rp[i] >> 17], 1);
    __syncthreads();

    // exclusive scan over 128
    if (tid < 128) sscan[tid] = cnt[tid];
    __syncthreads();
    for (int s = 1; s < 128; s <<= 1) {
        int t = 0;
        if (tid < 128 && tid >= s) t = sscan[tid - s];
        __syncthreads();
        if (tid < 128 && tid >= s) sscan[tid] += t;
        __syncthreads();
    }
    if (tid < 128) {
        int excl = sscan[tid] - cnt[tid];
        rptr[tid] = excl;
        cur[tid] = excl;
        if (tid == 127) rptr[128] = sscan[127];
    }
    __syncthreads();

    // scatter cols into window-local CSR
    for (int i = tid; i < n; i += 512) {
        unsigned int rcv = rp[i];
        int p = atomicAdd(&cur[rcv >> 17], 1);
        lcols[p] = (int)(rcv & 0x1FFFF);
    }
    __syncthreads();

    // one quad per row: register accumulate, dual accumulators
    const int q = tid >> 2;          // 0..127
    const int lane = tid & 3;
    const int node = row0 + q;
    float4 acc = make_float4(0.f, 0.f, 0.f, 0.f);
    float4 acc2 = make_float4(0.f, 0.f, 0.f, 0.f);
    int e = rptr[q];
    const int e1 = rptr[q + 1];
    for (; e + 4 <= e1; e += 4) {
        int c0 = lcols[e], c1 = lcols[e + 1], c2 = lcols[e + 2], c3 = lcols[e + 3];
        uint2 v0 = src[(size_t)c0 * 4 + lane];
        uint2 v1 = src[(size_t)c1 * 4 + lane];
        uint2 v2 = src[(size_t)c2 * 4 + lane];
        uint2 v3 = src[(size_t)c3 * 4 + lane];
        acc_half4(acc, v0);
        acc_half4(acc2, v1);
        acc_half4(acc, v2);
        acc_half4(acc2, v3);
    }
    for (; e < e1; ++e) {
        uint2 v = src[(size_t)lcols[e] * 4 + lane];
        acc_half4(acc, v);
    }
    acc.x += acc2.x; acc.y += acc2.y; acc.z += acc2.z; acc.w += acc2.w;

    if (!POOL) {
        if (node < N) {
            __half2 h01 = __floats2half2_rn(acc.x, acc.y);
            __half2 h23 = __floats2half2_rn(acc.z, acc.w);
            uint2 pkd;
            pkd.x = *(unsigned int*)&h01;
            pkd.y = *(unsigned int*)&h23;
            dst[(size_t)node * 4 + lane] = pkd;
        }
    } else {
        int g_first = sbatch[0];
        if (node < N) {
            int g = sbatch[q];
            int idx = g - g_first;
            if (idx < 32) {
                float* sp = &spool[idx * PC + lane * 4];
                atomicAdd(sp + 0, acc.x);
                atomicAdd(sp + 1, acc.y);
                atomicAdd(sp + 2, acc.z);
                atomicAdd(sp + 3, acc.w);
                if (lane == 0) atomicAdd(&spcnt[idx], 1);
            } else {
                float* pp = pooled + (size_t)g * PC + lane * 4;
                unsafeAtomicAdd(pp + 0, acc.x);
                unsafeAtomicAdd(pp + 1, acc.y);
                unsafeAtomicAdd(pp + 2, acc.z);
                unsafeAtomicAdd(pp + 3, acc.w);
                if (lane == 0) atomicAdd(&gcount[g], 1);
            }
        }
        __syncthreads();
        int lastrl = min(row0 + 127, N - 1) - row0;
        int span = min(sbatch[lastrl] - g_first + 1, 32);
        for (int t = tid; t < span * PC; t += 512) {
            float v = spool[t];
            if (v != 0.f)
                unsafeAtomicAdd(&pooled[(size_t)(g_first + (t >> 4)) * PC + (t & 15)], v);
        }
        if (tid < span && spcnt[tid] > 0)
            atomicAdd(&gcount[g_first + tid], spcnt[tid]);

        // ---- last-block-done: compute final output ----
        __threadfence();
        if (tid == 0) is_last = (atomicAdd(ticket, 1) == gridDim.x - 1);
        __syncthreads();
        if (is_last) {
            for (int i = tid; i < GG * CC; i += 512) {
                int g = i / CC, c = i % CC;
                float s = atomicAdd(&pooled[(size_t)g * PC + c], 0.0f);  // coherent read
                int cg = atomicAdd(&gcount[g], 0);                        // coherent read
                out[i] = s / (float)(cg > 0 ? cg : 1) + bvec[c];
            }
        }
    }
}

// ---------- launch ----------

static inline size_t al256(size_t x) { return (x + 255) & ~(size_t)255; }

extern "C" void kernel_launch(void* const* d_in, const int* in_sizes, int n_in,
                              void* d_out, int out_size, void* d_ws, size_t ws_size,
                              hipStream_t stream) {
    const float* x    = (const float*)d_in[0];
    const int*   eidx = (const int*)d_in[1];   // [2][E]: row then col
    const int*   batch= (const int*)d_in[2];
    const float* W    = (const float*)d_in[3];
    const float* bvec = (const float*)d_in[4];
    float* out = (float*)d_out;

    char* p = (char*)d_ws;
    float* pooled = (float*)p; p += al256((size_t)GG * PC * 4);
    int*   wfill  = (int*)p;   p += al256((size_t)NW * 4);
    int*   gcount = (int*)p;   p += al256((size_t)GG * 4);
    int*   ticket = (int*)p;   p += al256(256);
    size_t zbytes = (size_t)(p - (char*)d_ws);      // zeroed every call
    unsigned int* rec = (unsigned int*)p; p += al256((size_t)NW * WCAP * 4);
    uint2* y0     = (uint2*)p; p += al256((size_t)NW * 128 * 32);   // fp16 [N][16]
    uint2* y1     = (uint2*)p; p += al256((size_t)NW * 128 * 32);

    hipMemsetAsync(d_ws, 0, zbytes, stream);

    const int PB = (EE + EPB - 1) / EPB;   // 196
    partition_edges<<<PB, 1024, 0, stream>>>(eidx, wfill, rec, EE);

    xw_kernel<<<(NN + 63) / 64, 256, 0, stream>>>((const float4*)x, W, y0, NN);

    window_spmm<false><<<NW, 512, 0, stream>>>(y0, rec, wfill, nullptr,
                                               y1, nullptr, nullptr, nullptr,
                                               nullptr, nullptr, NN);

    window_spmm<true><<<NW, 512, 0, stream>>>(y1, rec, wfill, batch,
                                              nullptr, pooled, gcount, ticket,
                                              bvec, out, NN);
}

// Round 8
// 79.313 us; speedup vs baseline: 2.1067x; 2.1067x over previous
//
#include <hip/hip_runtime.h>
#include <hip/hip_fp16.h>

#define NN 100000
#define EE 1600000
#define FF 128
#define CC 10
#define GG 256
#define PC 16        // padded channels
#define WSH 7        // rows per window = 128
#define NW 782       // ceil(NN / 128)
#define WCAP 2560    // records per window capacity (mean 2046, +11 sigma)
#define EPB 8192     // edges per partition block (196 blocks)

// ---------- partition: sort 8K edges in LDS by window, write contiguous segments ----------

__global__ __launch_bounds__(1024) void partition_edges(
        const int* __restrict__ eidx, int* __restrict__ wfill,
        unsigned int* __restrict__ rec, int E) {
    __shared__ unsigned int srec[EPB];          // 32 KB
    __shared__ unsigned short sw[EPB];          // 16 KB
    __shared__ int lcnt[NW];
    __shared__ int lofs[NW];
    __shared__ int lcur[NW];
    __shared__ int lgb[NW];
    __shared__ int sscan[1024];
    const int tid = threadIdx.x;
    const int e0 = blockIdx.x * EPB;
    const int n = min(EPB, E - e0);

    for (int i = tid; i < NW; i += 1024) lcnt[i] = 0;
    __syncthreads();

    // load this thread's (up to) 8 edges into registers + histogram
    int rr[8], cc[8];
    #pragma unroll
    for (int k = 0; k < 8; ++k) {
        int i = tid + (k << 10);
        if (i < n) {
            rr[k] = eidx[e0 + i];
            cc[k] = eidx[EE + e0 + i];
            atomicAdd(&lcnt[rr[k] >> WSH], 1);
        }
    }
    __syncthreads();

    sscan[tid] = (tid < NW) ? lcnt[tid] : 0;
    __syncthreads();
    for (int s = 1; s < 1024; s <<= 1) {
        int t = 0;
        if (tid >= s) t = sscan[tid - s];
        __syncthreads();
        if (tid >= s) sscan[tid] += t;
        __syncthreads();
    }
    if (tid < NW) {
        int excl = sscan[tid] - lcnt[tid];
        lofs[tid] = excl;
        lcur[tid] = excl;
    }
    __syncthreads();

    // scatter into LDS sorted-by-window
    #pragma unroll
    for (int k = 0; k < 8; ++k) {
        int i = tid + (k << 10);
        if (i < n) {
            int w = rr[k] >> WSH;
            int p = atomicAdd(&lcur[w], 1);
            srec[p] = ((unsigned int)(rr[k] & 127) << 17) | (unsigned int)cc[k];
            sw[p] = (unsigned short)w;
        }
    }
    __syncthreads();

    // reserve global segments
    if (tid < NW) {
        int cw = lcnt[tid];
        lgb[tid] = cw ? atomicAdd(&wfill[tid], cw) : 0;
    }
    __syncthreads();

    // write contiguous runs
    for (int i = tid; i < n; i += 1024) {
        int w = sw[i];
        int pos = lgb[w] + (i - lofs[w]);
        if (pos < WCAP) rec[(size_t)w * WCAP + pos] = srec[i];
    }
}

// ---------- y0 = x @ W (quad per node), output packed fp16 [N][16] (32B rows) ----------

__global__ void xw_kernel(const float4* __restrict__ x4,   // [N][32]
                          const float* __restrict__ W,     // [128][10]
                          uint2* __restrict__ y0,          // [N][4] x 8B (fp16x4)
                          int N) {
    __shared__ float4 WT[CC][32];   // WT[c][k] = W[4k..4k+3][c]
    for (int i = threadIdx.x; i < CC * 32; i += blockDim.x) {
        int c = i >> 5, k = i & 31;
        WT[c][k] = make_float4(W[(4 * k + 0) * CC + c], W[(4 * k + 1) * CC + c],
                               W[(4 * k + 2) * CC + c], W[(4 * k + 3) * CC + c]);
    }
    __syncthreads();
    int node = blockIdx.x * 64 + (threadIdx.x >> 2);
    int lane = threadIdx.x & 3;
    if (node >= N) return;
    float a[CC];
    #pragma unroll
    for (int c = 0; c < CC; ++c) a[c] = 0.f;
    #pragma unroll
    for (int k = 0; k < 8; ++k) {
        float4 xv = x4[(size_t)node * 32 + k * 4 + lane];
        #pragma unroll
        for (int c = 0; c < CC; ++c) {
            float4 wv = WT[c][k * 4 + lane];
            a[c] += xv.x * wv.x + xv.y * wv.y + xv.z * wv.z + xv.w * wv.w;
        }
    }
    #pragma unroll
    for (int c = 0; c < CC; ++c) {
        a[c] += __shfl_xor(a[c], 1);
        a[c] += __shfl_xor(a[c], 2);
    }
    float4 o;
    if (lane == 0)      o = make_float4(a[0], a[1], a[2], a[3]);
    else if (lane == 1) o = make_float4(a[4], a[5], a[6], a[7]);
    else if (lane == 2) o = make_float4(a[8], a[9], 0.f, 0.f);
    else                o = make_float4(0.f, 0.f, 0.f, 0.f);
    __half2 h01 = __floats2half2_rn(o.x, o.y);
    __half2 h23 = __floats2half2_rn(o.z, o.w);
    uint2 pkd;
    pkd.x = *(unsigned int*)&h01;
    pkd.y = *(unsigned int*)&h23;
    y0[(size_t)node * 4 + lane] = pkd;
}

__device__ __forceinline__ void acc_half4(float4& acc, uint2 v) {
    __half2 h0 = *(__half2*)&v.x;
    __half2 h1 = *(__half2*)&v.y;
    float2 f0 = __half22float2(h0);
    float2 f1 = __half22float2(h1);
    acc.x += f0.x; acc.y += f0.y; acc.z += f1.x; acc.w += f1.y;
}

// ---------- window SpMM: local CSR in LDS, register accumulate per row ----------
// POOL=false: write fp16 dst rows.
// POOL=true: fuse per-graph pooling (sums + counts). NO fence/ticket — finalize
// is a separate launch (782 device-scope fences cost ~100us on 8-XCD parts).

template<bool POOL>
__global__ __launch_bounds__(512) void window_spmm(
        const uint2* __restrict__ src,             // [N][4] fp16x4
        const unsigned int* __restrict__ rec,
        const int* __restrict__ wfill, const int* __restrict__ batch,
        uint2* __restrict__ dst, float* __restrict__ pooled,
        int* __restrict__ gcount, int N) {
    __shared__ int cnt[128];
    __shared__ int sscan[128];
    __shared__ int rptr[129];
    __shared__ int cur[128];
    __shared__ int lcols[WCAP];        // 10 KB
    __shared__ float spool[32 * PC];
    __shared__ int spcnt[32];
    __shared__ int sbatch[128];

    const int tid = threadIdx.x;
    const int w = blockIdx.x;
    const int row0 = w << WSH;
    const int n = min(wfill[w], WCAP);
    const unsigned int* rp = rec + (size_t)w * WCAP;

    if (tid < 128) {
        cnt[tid] = 0;
        if (POOL) {
            int node = row0 + tid;
            sbatch[tid] = (node < N) ? batch[node] : -1;
        }
    }
    if (POOL) {
        for (int i = tid; i < 32 * PC; i += 512) spool[i] = 0.f;
        if (tid < 32) spcnt[tid] = 0;
    }
    __syncthreads();

    // histogram rows
    for (int i = tid; i < n; i += 512)
        atomicAdd(&cnt[rp[i] >> 17], 1);
    __syncthreads();

    // exclusive scan over 128
    if (tid < 128) sscan[tid] = cnt[tid];
    __syncthreads();
    for (int s = 1; s < 128; s <<= 1) {
        int t = 0;
        if (tid < 128 && tid >= s) t = sscan[tid - s];
        __syncthreads();
        if (tid < 128 && tid >= s) sscan[tid] += t;
        __syncthreads();
    }
    if (tid < 128) {
        int excl = sscan[tid] - cnt[tid];
        rptr[tid] = excl;
        cur[tid] = excl;
        if (tid == 127) rptr[128] = sscan[127];
    }
    __syncthreads();

    // scatter cols into window-local CSR
    for (int i = tid; i < n; i += 512) {
        unsigned int rcv = rp[i];
        int p = atomicAdd(&cur[rcv >> 17], 1);
        lcols[p] = (int)(rcv & 0x1FFFF);
    }
    __syncthreads();

    // one quad per row: register accumulate, dual accumulators
    const int q = tid >> 2;          // 0..127
    const int lane = tid & 3;
    const int node = row0 + q;
    float4 acc = make_float4(0.f, 0.f, 0.f, 0.f);
    float4 acc2 = make_float4(0.f, 0.f, 0.f, 0.f);
    int e = rptr[q];
    const int e1 = rptr[q + 1];
    for (; e + 4 <= e1; e += 4) {
        int c0 = lcols[e], c1 = lcols[e + 1], c2 = lcols[e + 2], c3 = lcols[e + 3];
        uint2 v0 = src[(size_t)c0 * 4 + lane];
        uint2 v1 = src[(size_t)c1 * 4 + lane];
        uint2 v2 = src[(size_t)c2 * 4 + lane];
        uint2 v3 = src[(size_t)c3 * 4 + lane];
        acc_half4(acc, v0);
        acc_half4(acc2, v1);
        acc_half4(acc, v2);
        acc_half4(acc2, v3);
    }
    for (; e < e1; ++e) {
        uint2 v = src[(size_t)lcols[e] * 4 + lane];
        acc_half4(acc, v);
    }
    acc.x += acc2.x; acc.y += acc2.y; acc.z += acc2.z; acc.w += acc2.w;

    if (!POOL) {
        if (node < N) {
            __half2 h01 = __floats2half2_rn(acc.x, acc.y);
            __half2 h23 = __floats2half2_rn(acc.z, acc.w);
            uint2 pkd;
            pkd.x = *(unsigned int*)&h01;
            pkd.y = *(unsigned int*)&h23;
            dst[(size_t)node * 4 + lane] = pkd;
        }
    } else {
        int g_first = sbatch[0];
        if (node < N) {
            int g = sbatch[q];
            int idx = g - g_first;
            if (idx < 32) {
                float* sp = &spool[idx * PC + lane * 4];
                atomicAdd(sp + 0, acc.x);
                atomicAdd(sp + 1, acc.y);
                atomicAdd(sp + 2, acc.z);
                atomicAdd(sp + 3, acc.w);
                if (lane == 0) atomicAdd(&spcnt[idx], 1);
            } else {
                float* pp = pooled + (size_t)g * PC + lane * 4;
                unsafeAtomicAdd(pp + 0, acc.x);
                unsafeAtomicAdd(pp + 1, acc.y);
                unsafeAtomicAdd(pp + 2, acc.z);
                unsafeAtomicAdd(pp + 3, acc.w);
                if (lane == 0) atomicAdd(&gcount[g], 1);
            }
        }
        __syncthreads();
        int lastrl = min(row0 + 127, N - 1) - row0;
        int span = min(sbatch[lastrl] - g_first + 1, 32);
        for (int t = tid; t < span * PC; t += 512) {
            float v = spool[t];
            if (v != 0.f)
                unsafeAtomicAdd(&pooled[(size_t)(g_first + (t >> 4)) * PC + (t & 15)], v);
        }
        if (tid < span && spcnt[tid] > 0)
            atomicAdd(&gcount[g_first + tid], spcnt[tid]);
    }
}

// ---------- finalize: out[g,c] = pooled[g,c]/max(gcount[g],1) + b[c] ----------

__global__ void finalize(const float* __restrict__ pooled, const int* __restrict__ gcount,
                         const float* __restrict__ bvec, float* __restrict__ out) {
    int idx = blockIdx.x * blockDim.x + threadIdx.x;
    if (idx >= GG * CC) return;
    int g = idx / CC, c = idx % CC;
    int cg = gcount[g];
    out[idx] = pooled[g * PC + c] / (float)(cg > 0 ? cg : 1) + bvec[c];
}

// ---------- launch ----------

static inline size_t al256(size_t x) { return (x + 255) & ~(size_t)255; }

extern "C" void kernel_launch(void* const* d_in, const int* in_sizes, int n_in,
                              void* d_out, int out_size, void* d_ws, size_t ws_size,
                              hipStream_t stream) {
    const float* x    = (const float*)d_in[0];
    const int*   eidx = (const int*)d_in[1];   // [2][E]: row then col
    const int*   batch= (const int*)d_in[2];
    const float* W    = (const float*)d_in[3];
    const float* bvec = (const float*)d_in[4];
    float* out = (float*)d_out;

    char* p = (char*)d_ws;
    float* pooled = (float*)p; p += al256((size_t)GG * PC * 4);
    int*   wfill  = (int*)p;   p += al256((size_t)NW * 4);
    int*   gcount = (int*)p;   p += al256((size_t)GG * 4);
    size_t zbytes = (size_t)(p - (char*)d_ws);      // zeroed every call
    unsigned int* rec = (unsigned int*)p; p += al256((size_t)NW * WCAP * 4);
    uint2* y0     = (uint2*)p; p += al256((size_t)NW * 128 * 32);   // fp16 [N][16]
    uint2* y1     = (uint2*)p; p += al256((size_t)NW * 128 * 32);

    hipMemsetAsync(d_ws, 0, zbytes, stream);

    const int PB = (EE + EPB - 1) / EPB;   // 196
    partition_edges<<<PB, 1024, 0, stream>>>(eidx, wfill, rec, EE);

    xw_kernel<<<(NN + 63) / 64, 256, 0, stream>>>((const float4*)x, W, y0, NN);

    window_spmm<false><<<NW, 512, 0, stream>>>(y0, rec, wfill, nullptr,
                                               y1, nullptr, nullptr, NN);

    window_spmm<true><<<NW, 512, 0, stream>>>(y1, rec, wfill, batch,
                                              nullptr, pooled, gcount, NN);

    finalize<<<(GG * CC + 255) / 256, 256, 0, stream>>>(pooled, gcount, bvec, out);
}

// Round 9
// 73.491 us; speedup vs baseline: 2.2736x; 1.0792x over previous
//
#include <hip/hip_runtime.h>
#include <hip/hip_fp16.h>

#define NN 100000
#define EE 1600000
#define FF 128
#define CC 10
#define GG 256
#define PC 16        // padded channels
#define WSH 7        // rows per window = 128
#define NW 782       // ceil(NN / 128)
#define WCAP 2560    // records per window capacity (mean 2046, +11 sigma)
#define EPB 8192     // edges per partition block
#define PB 196       // partition blocks = ceil(EE/EPB)
#define XB 391       // xw blocks (256 nodes each)

// ---------- merged prep kernel: blocks [0,PB) partition edges; [PB,PB+XB) compute x@W ----------

__global__ __launch_bounds__(1024) void prep(
        const int* __restrict__ eidx, int* __restrict__ wfill,
        unsigned int* __restrict__ rec,
        const float4* __restrict__ x4, const float* __restrict__ W,
        uint2* __restrict__ y0, int E, int N) {
    __shared__ alignas(16) union {
        struct {
            unsigned int srec[EPB];      // 32 KB
            unsigned short sw[EPB];      // 16 KB
            int lcnt[NW];
            int lofs[NW];
            int lcur[NW];
            int lgb[NW];                 // 12.5 KB
            int sscan[1024];             // 4 KB
        } p;
        float wt[CC * FF];               // 5 KB (float4-viewed WT[c][k])
    } u;

    const int tid = threadIdx.x;

    if (blockIdx.x < PB) {
        // ================= partition role =================
        const int e0 = blockIdx.x * EPB;
        const int n = min(EPB, E - e0);

        for (int i = tid; i < NW; i += 1024) u.p.lcnt[i] = 0;
        __syncthreads();

        // load this thread's (up to) 8 edges into registers + histogram
        int rr[8], cc[8];
        #pragma unroll
        for (int k = 0; k < 8; ++k) {
            int i = tid + (k << 10);
            if (i < n) {
                rr[k] = eidx[e0 + i];
                cc[k] = eidx[EE + e0 + i];
                atomicAdd(&u.p.lcnt[rr[k] >> WSH], 1);
            }
        }
        __syncthreads();

        u.p.sscan[tid] = (tid < NW) ? u.p.lcnt[tid] : 0;
        __syncthreads();
        for (int s = 1; s < 1024; s <<= 1) {
            int t = 0;
            if (tid >= s) t = u.p.sscan[tid - s];
            __syncthreads();
            if (tid >= s) u.p.sscan[tid] += t;
            __syncthreads();
        }
        if (tid < NW) {
            int excl = u.p.sscan[tid] - u.p.lcnt[tid];
            u.p.lofs[tid] = excl;
            u.p.lcur[tid] = excl;
        }
        __syncthreads();

        // scatter into LDS sorted-by-window
        #pragma unroll
        for (int k = 0; k < 8; ++k) {
            int i = tid + (k << 10);
            if (i < n) {
                int w = rr[k] >> WSH;
                int p = atomicAdd(&u.p.lcur[w], 1);
                u.p.srec[p] = ((unsigned int)(rr[k] & 127) << 17) | (unsigned int)cc[k];
                u.p.sw[p] = (unsigned short)w;
            }
        }
        __syncthreads();

        // reserve global segments
        if (tid < NW) {
            int cw = u.p.lcnt[tid];
            u.p.lgb[tid] = cw ? atomicAdd(&wfill[tid], cw) : 0;
        }
        __syncthreads();

        // write contiguous runs
        for (int i = tid; i < n; i += 1024) {
            int w = u.p.sw[i];
            int pos = u.p.lgb[w] + (i - u.p.lofs[w]);
            if (pos < WCAP) rec[(size_t)w * WCAP + pos] = u.p.srec[i];
        }
    } else {
        // ================= xw role: y0 = x @ W (fp16 packed) =================
        float4* WT = (float4*)u.wt;    // WT[c*32 + k]
        for (int i = tid; i < CC * 32; i += 1024) {
            int c = i >> 5, k = i & 31;
            WT[i >> 5 == c ? c * 32 + k : 0] = make_float4(
                W[(4 * k + 0) * CC + c], W[(4 * k + 1) * CC + c],
                W[(4 * k + 2) * CC + c], W[(4 * k + 3) * CC + c]);
        }
        __syncthreads();
        int node = (blockIdx.x - PB) * 256 + (tid >> 2);
        int lane = tid & 3;
        if (node >= N) return;
        float a[CC];
        #pragma unroll
        for (int c = 0; c < CC; ++c) a[c] = 0.f;
        #pragma unroll
        for (int k = 0; k < 8; ++k) {
            float4 xv = x4[(size_t)node * 32 + k * 4 + lane];
            #pragma unroll
            for (int c = 0; c < CC; ++c) {
                float4 wv = WT[c * 32 + k * 4 + lane];
                a[c] += xv.x * wv.x + xv.y * wv.y + xv.z * wv.z + xv.w * wv.w;
            }
        }
        #pragma unroll
        for (int c = 0; c < CC; ++c) {
            a[c] += __shfl_xor(a[c], 1);
            a[c] += __shfl_xor(a[c], 2);
        }
        float4 o;
        if (lane == 0)      o = make_float4(a[0], a[1], a[2], a[3]);
        else if (lane == 1) o = make_float4(a[4], a[5], a[6], a[7]);
        else if (lane == 2) o = make_float4(a[8], a[9], 0.f, 0.f);
        else                o = make_float4(0.f, 0.f, 0.f, 0.f);
        __half2 h01 = __floats2half2_rn(o.x, o.y);
        __half2 h23 = __floats2half2_rn(o.z, o.w);
        uint2 pkd;
        pkd.x = *(unsigned int*)&h01;
        pkd.y = *(unsigned int*)&h23;
        y0[(size_t)node * 4 + lane] = pkd;
    }
}

__device__ __forceinline__ void acc_half4(float4& acc, uint2 v) {
    __half2 h0 = *(__half2*)&v.x;
    __half2 h1 = *(__half2*)&v.y;
    float2 f0 = __half22float2(h0);
    float2 f1 = __half22float2(h1);
    acc.x += f0.x; acc.y += f0.y; acc.z += f1.x; acc.w += f1.y;
}

// ---------- window SpMM: local CSR in LDS, register accumulate per row ----------
// POOL=false: write fp16 dst rows.
// POOL=true: fuse per-graph pooling (sums + counts). No fence/ticket (R7 lesson:
// 782 device-scope fences cost ~100us on 8-XCD parts; a launch is cheaper).

template<bool POOL>
__global__ __launch_bounds__(512) void window_spmm(
        const uint2* __restrict__ src,             // [N][4] fp16x4
        const unsigned int* __restrict__ rec,
        const int* __restrict__ wfill, const int* __restrict__ batch,
        uint2* __restrict__ dst, float* __restrict__ pooled,
        int* __restrict__ gcount, int N) {
    __shared__ int cnt[128];
    __shared__ int sscan[128];
    __shared__ int rptr[129];
    __shared__ int cur[128];
    __shared__ int lcols[WCAP];        // 10 KB
    __shared__ float spool[32 * PC];
    __shared__ int spcnt[32];
    __shared__ int sbatch[128];

    const int tid = threadIdx.x;
    const int w = blockIdx.x;
    const int row0 = w << WSH;
    const int n = min(wfill[w], WCAP);
    const unsigned int* rp = rec + (size_t)w * WCAP;

    if (tid < 128) {
        cnt[tid] = 0;
        if (POOL) {
            int node = row0 + tid;
            sbatch[tid] = (node < N) ? batch[node] : -1;
        }
    }
    if (POOL) {
        for (int i = tid; i < 32 * PC; i += 512) spool[i] = 0.f;
        if (tid < 32) spcnt[tid] = 0;
    }
    __syncthreads();

    // histogram rows
    for (int i = tid; i < n; i += 512)
        atomicAdd(&cnt[rp[i] >> 17], 1);
    __syncthreads();

    // exclusive scan over 128
    if (tid < 128) sscan[tid] = cnt[tid];
    __syncthreads();
    for (int s = 1; s < 128; s <<= 1) {
        int t = 0;
        if (tid < 128 && tid >= s) t = sscan[tid - s];
        __syncthreads();
        if (tid < 128 && tid >= s) sscan[tid] += t;
        __syncthreads();
    }
    if (tid < 128) {
        int excl = sscan[tid] - cnt[tid];
        rptr[tid] = excl;
        cur[tid] = excl;
        if (tid == 127) rptr[128] = sscan[127];
    }
    __syncthreads();

    // scatter cols into window-local CSR
    for (int i = tid; i < n; i += 512) {
        unsigned int rcv = rp[i];
        int p = atomicAdd(&cur[rcv >> 17], 1);
        lcols[p] = (int)(rcv & 0x1FFFF);
    }
    __syncthreads();

    // one quad per row: register accumulate, dual accumulators
    const int q = tid >> 2;          // 0..127
    const int lane = tid & 3;
    const int node = row0 + q;
    float4 acc = make_float4(0.f, 0.f, 0.f, 0.f);
    float4 acc2 = make_float4(0.f, 0.f, 0.f, 0.f);
    int e = rptr[q];
    const int e1 = rptr[q + 1];
    for (; e + 4 <= e1; e += 4) {
        int c0 = lcols[e], c1 = lcols[e + 1], c2 = lcols[e + 2], c3 = lcols[e + 3];
        uint2 v0 = src[(size_t)c0 * 4 + lane];
        uint2 v1 = src[(size_t)c1 * 4 + lane];
        uint2 v2 = src[(size_t)c2 * 4 + lane];
        uint2 v3 = src[(size_t)c3 * 4 + lane];
        acc_half4(acc, v0);
        acc_half4(acc2, v1);
        acc_half4(acc, v2);
        acc_half4(acc2, v3);
    }
    for (; e < e1; ++e) {
        uint2 v = src[(size_t)lcols[e] * 4 + lane];
        acc_half4(acc, v);
    }
    acc.x += acc2.x; acc.y += acc2.y; acc.z += acc2.z; acc.w += acc2.w;

    if (!POOL) {
        if (node < N) {
            __half2 h01 = __floats2half2_rn(acc.x, acc.y);
            __half2 h23 = __floats2half2_rn(acc.z, acc.w);
            uint2 pkd;
            pkd.x = *(unsigned int*)&h01;
            pkd.y = *(unsigned int*)&h23;
            dst[(size_t)node * 4 + lane] = pkd;
        }
    } else {
        int g_first = sbatch[0];
        if (node < N) {
            int g = sbatch[q];
            int idx = g - g_first;
            if (idx < 32) {
                float* sp = &spool[idx * PC + lane * 4];
                atomicAdd(sp + 0, acc.x);
                atomicAdd(sp + 1, acc.y);
                atomicAdd(sp + 2, acc.z);
                atomicAdd(sp + 3, acc.w);
                if (lane == 0) atomicAdd(&spcnt[idx], 1);
            } else {
                float* pp = pooled + (size_t)g * PC + lane * 4;
                unsafeAtomicAdd(pp + 0, acc.x);
                unsafeAtomicAdd(pp + 1, acc.y);
                unsafeAtomicAdd(pp + 2, acc.z);
                unsafeAtomicAdd(pp + 3, acc.w);
                if (lane == 0) atomicAdd(&gcount[g], 1);
            }
        }
        __syncthreads();
        int lastrl = min(row0 + 127, N - 1) - row0;
        int span = min(sbatch[lastrl] - g_first + 1, 32);
        for (int t = tid; t < span * PC; t += 512) {
            float v = spool[t];
            if (v != 0.f)
                unsafeAtomicAdd(&pooled[(size_t)(g_first + (t >> 4)) * PC + (t & 15)], v);
        }
        if (tid < span && spcnt[tid] > 0)
            atomicAdd(&gcount[g_first + tid], spcnt[tid]);
    }
}

// ---------- finalize: out[g,c] = pooled[g,c]/max(gcount[g],1) + b[c] ----------

__global__ void finalize(const float* __restrict__ pooled, const int* __restrict__ gcount,
                         const float* __restrict__ bvec, float* __restrict__ out) {
    int idx = blockIdx.x * blockDim.x + threadIdx.x;
    if (idx >= GG * CC) return;
    int g = idx / CC, c = idx % CC;
    int cg = gcount[g];
    out[idx] = pooled[g * PC + c] / (float)(cg > 0 ? cg : 1) + bvec[c];
}

// ---------- launch ----------

static inline size_t al256(size_t x) { return (x + 255) & ~(size_t)255; }

extern "C" void kernel_launch(void* const* d_in, const int* in_sizes, int n_in,
                              void* d_out, int out_size, void* d_ws, size_t ws_size,
                              hipStream_t stream) {
    const float* x    = (const float*)d_in[0];
    const int*   eidx = (const int*)d_in[1];   // [2][E]: row then col
    const int*   batch= (const int*)d_in[2];
    const float* W    = (const float*)d_in[3];
    const float* bvec = (const float*)d_in[4];
    float* out = (float*)d_out;

    char* p = (char*)d_ws;
    float* pooled = (float*)p; p += al256((size_t)GG * PC * 4);
    int*   wfill  = (int*)p;   p += al256((size_t)NW * 4);
    int*   gcount = (int*)p;   p += al256((size_t)GG * 4);
    size_t zbytes = (size_t)(p - (char*)d_ws);      // zeroed every call
    unsigned int* rec = (unsigned int*)p; p += al256((size_t)NW * WCAP * 4);
    uint2* y0     = (uint2*)p; p += al256((size_t)NW * 128 * 32);   // fp16 [N][16]
    uint2* y1     = (uint2*)p; p += al256((size_t)NW * 128 * 32);

    hipMemsetAsync(d_ws, 0, zbytes, stream);

    prep<<<PB + XB, 1024, 0, stream>>>(eidx, wfill, rec,
                                       (const float4*)x, W, y0, EE, NN);

    window_spmm<false><<<NW, 512, 0, stream>>>(y0, rec, wfill, nullptr,
                                               y1, nullptr, nullptr, NN);

    window_spmm<true><<<NW, 512, 0, stream>>>(y1, rec, wfill, batch,
                                              nullptr, pooled, gcount, NN);

    finalize<<<(GG * CC + 255) / 256, 256, 0, stream>>>(pooled, gcount, bvec, out);
}

// Round 10
// 69.994 us; speedup vs baseline: 2.3872x; 1.0500x over previous
//
#include <hip/hip_runtime.h>
#include <hip/hip_fp16.h>

#define NN 100000
#define EE 1600000
#define FF 128
#define CC 10
#define GG 256
#define PC 16        // padded channels
#define WSH 7        // rows per window = 128
#define NW 782       // ceil(NN / 128)
#define WCAP 2560    // records per window capacity (mean 2046, +11 sigma)
#define EPB 8192     // edges per partition block
#define PB 196       // partition blocks = ceil(EE/EPB)
#define XB 391       // xw blocks (256 nodes each)

// ---------- merged prep kernel: blocks [0,PB) partition edges; [PB,PB+XB) compute x@W ----------

__global__ __launch_bounds__(1024) void prep(
        const int* __restrict__ eidx, int* __restrict__ wfill,
        unsigned int* __restrict__ rec,
        const float4* __restrict__ x4, const float* __restrict__ W,
        uint2* __restrict__ y0, float* __restrict__ pooled,
        int* __restrict__ gcount, int E, int N) {
    __shared__ alignas(16) union {
        struct {
            unsigned int srec[EPB];      // 32 KB
            unsigned short sw[EPB];      // 16 KB
            int lcnt[NW];
            int lofs[NW];
            int lcur[NW];
            int lgb[NW];                 // 12.5 KB
            int sscan[1024];             // 4 KB
        } p;
        float wt[CC * FF];               // 5 KB (float4-viewed WT[c][k])
    } u;

    const int tid = threadIdx.x;

    if (blockIdx.x < PB) {
        // ================= partition role =================
        const int e0 = blockIdx.x * EPB;
        const int n = min(EPB, E - e0);

        for (int i = tid; i < NW; i += 1024) u.p.lcnt[i] = 0;
        __syncthreads();

        // load this thread's (up to) 8 edges into registers + histogram
        int rr[8], cc[8];
        #pragma unroll
        for (int k = 0; k < 8; ++k) {
            int i = tid + (k << 10);
            if (i < n) {
                rr[k] = eidx[e0 + i];
                cc[k] = eidx[EE + e0 + i];
                atomicAdd(&u.p.lcnt[rr[k] >> WSH], 1);
            }
        }
        __syncthreads();

        u.p.sscan[tid] = (tid < NW) ? u.p.lcnt[tid] : 0;
        __syncthreads();
        for (int s = 1; s < 1024; s <<= 1) {
            int t = 0;
            if (tid >= s) t = u.p.sscan[tid - s];
            __syncthreads();
            if (tid >= s) u.p.sscan[tid] += t;
            __syncthreads();
        }
        if (tid < NW) {
            int excl = u.p.sscan[tid] - u.p.lcnt[tid];
            u.p.lofs[tid] = excl;
            u.p.lcur[tid] = excl;
        }
        __syncthreads();

        // scatter into LDS sorted-by-window
        #pragma unroll
        for (int k = 0; k < 8; ++k) {
            int i = tid + (k << 10);
            if (i < n) {
                int w = rr[k] >> WSH;
                int p = atomicAdd(&u.p.lcur[w], 1);
                u.p.srec[p] = ((unsigned int)(rr[k] & 127) << 17) | (unsigned int)cc[k];
                u.p.sw[p] = (unsigned short)w;
            }
        }
        __syncthreads();

        // reserve global segments
        if (tid < NW) {
            int cw = u.p.lcnt[tid];
            u.p.lgb[tid] = cw ? atomicAdd(&wfill[tid], cw) : 0;
        }
        __syncthreads();

        // write contiguous runs
        for (int i = tid; i < n; i += 1024) {
            int w = u.p.sw[i];
            int pos = u.p.lgb[w] + (i - u.p.lofs[w]);
            if (pos < WCAP) rec[(size_t)w * WCAP + pos] = u.p.srec[i];
        }
    } else {
        // ================= xw role: y0 = x @ W (fp16 packed) =================
        if (blockIdx.x == PB) {      // also zero the pool accumulators (pre-spmm<true>)
            for (int i = tid; i < GG * PC; i += 1024) pooled[i] = 0.f;
            if (tid < GG) gcount[tid] = 0;
        }
        float4* WT = (float4*)u.wt;    // WT[c*32 + k]
        for (int i = tid; i < CC * 32; i += 1024) {
            int c = i >> 5, k = i & 31;
            WT[c * 32 + k] = make_float4(
                W[(4 * k + 0) * CC + c], W[(4 * k + 1) * CC + c],
                W[(4 * k + 2) * CC + c], W[(4 * k + 3) * CC + c]);
        }
        __syncthreads();
        int node = (blockIdx.x - PB) * 256 + (tid >> 2);
        int lane = tid & 3;
        if (node >= N) return;
        float a[CC];
        #pragma unroll
        for (int c = 0; c < CC; ++c) a[c] = 0.f;
        #pragma unroll
        for (int k = 0; k < 8; ++k) {
            float4 xv = x4[(size_t)node * 32 + k * 4 + lane];
            #pragma unroll
            for (int c = 0; c < CC; ++c) {
                float4 wv = WT[c * 32 + k * 4 + lane];
                a[c] += xv.x * wv.x + xv.y * wv.y + xv.z * wv.z + xv.w * wv.w;
            }
        }
        #pragma unroll
        for (int c = 0; c < CC; ++c) {
            a[c] += __shfl_xor(a[c], 1);
            a[c] += __shfl_xor(a[c], 2);
        }
        float4 o;
        if (lane == 0)      o = make_float4(a[0], a[1], a[2], a[3]);
        else if (lane == 1) o = make_float4(a[4], a[5], a[6], a[7]);
        else if (lane == 2) o = make_float4(a[8], a[9], 0.f, 0.f);
        else                o = make_float4(0.f, 0.f, 0.f, 0.f);
        __half2 h01 = __floats2half2_rn(o.x, o.y);
        __half2 h23 = __floats2half2_rn(o.z, o.w);
        uint2 pkd;
        pkd.x = *(unsigned int*)&h01;
        pkd.y = *(unsigned int*)&h23;
        y0[(size_t)node * 4 + lane] = pkd;
    }
}

__device__ __forceinline__ void acc_half4(float4& acc, uint2 v) {
    __half2 h0 = *(__half2*)&v.x;
    __half2 h1 = *(__half2*)&v.y;
    float2 f0 = __half22float2(h0);
    float2 f1 = __half22float2(h1);
    acc.x += f0.x; acc.y += f0.y; acc.z += f1.x; acc.w += f1.y;
}

// ---------- window SpMM: local CSR in LDS, register accumulate per row ----------
// Records register-cached (one global read instead of two). 8-wide gather unroll,
// 4 accumulators. POOL=false: write fp16 dst rows. POOL=true: per-graph pooling.
// No fence/ticket (R7 lesson: 782 device fences ~100us; a launch is cheaper).

template<bool POOL>
__global__ __launch_bounds__(512) void window_spmm(
        const uint2* __restrict__ src,             // [N][4] fp16x4
        const unsigned int* __restrict__ rec,
        const int* __restrict__ wfill, const int* __restrict__ batch,
        uint2* __restrict__ dst, float* __restrict__ pooled,
        int* __restrict__ gcount, int N) {
    __shared__ int cnt[128];
    __shared__ int sscan[128];
    __shared__ int rptr[129];
    __shared__ int cur[128];
    __shared__ int lcols[WCAP];        // 10 KB
    __shared__ float spool[32 * PC];
    __shared__ int spcnt[32];
    __shared__ int sbatch[128];

    const int tid = threadIdx.x;
    const int w = blockIdx.x;
    const int row0 = w << WSH;
    const int n = min(wfill[w], WCAP);
    const unsigned int* rp = rec + (size_t)w * WCAP;

    if (tid < 128) {
        cnt[tid] = 0;
        if (POOL) {
            int node = row0 + tid;
            sbatch[tid] = (node < N) ? batch[node] : -1;
        }
    }
    if (POOL) {
        for (int i = tid; i < 32 * PC; i += 512) spool[i] = 0.f;
        if (tid < 32) spcnt[tid] = 0;
    }
    __syncthreads();

    // register-cache this thread's <=5 records (named regs, no runtime indexing)
    const int i1 = tid + 512, i2 = tid + 1024, i3 = tid + 1536, i4 = tid + 2048;
    unsigned int r0 = 0, r1 = 0, r2 = 0, r3 = 0, r4 = 0;
    if (tid < n) r0 = rp[tid];
    if (i1 < n) r1 = rp[i1];
    if (i2 < n) r2 = rp[i2];
    if (i3 < n) r3 = rp[i3];
    if (i4 < n) r4 = rp[i4];

    // histogram rows from registers
    if (tid < n) atomicAdd(&cnt[r0 >> 17], 1);
    if (i1 < n) atomicAdd(&cnt[r1 >> 17], 1);
    if (i2 < n) atomicAdd(&cnt[r2 >> 17], 1);
    if (i3 < n) atomicAdd(&cnt[r3 >> 17], 1);
    if (i4 < n) atomicAdd(&cnt[r4 >> 17], 1);
    __syncthreads();

    // exclusive scan over 128
    if (tid < 128) sscan[tid] = cnt[tid];
    __syncthreads();
    for (int s = 1; s < 128; s <<= 1) {
        int t = 0;
        if (tid < 128 && tid >= s) t = sscan[tid - s];
        __syncthreads();
        if (tid < 128 && tid >= s) sscan[tid] += t;
        __syncthreads();
    }
    if (tid < 128) {
        int excl = sscan[tid] - cnt[tid];
        rptr[tid] = excl;
        cur[tid] = excl;
        if (tid == 127) rptr[128] = sscan[127];
    }
    __syncthreads();

    // scatter cols into window-local CSR from registers
    if (tid < n) { int p = atomicAdd(&cur[r0 >> 17], 1); lcols[p] = (int)(r0 & 0x1FFFF); }
    if (i1 < n) { int p = atomicAdd(&cur[r1 >> 17], 1); lcols[p] = (int)(r1 & 0x1FFFF); }
    if (i2 < n) { int p = atomicAdd(&cur[r2 >> 17], 1); lcols[p] = (int)(r2 & 0x1FFFF); }
    if (i3 < n) { int p = atomicAdd(&cur[r3 >> 17], 1); lcols[p] = (int)(r3 & 0x1FFFF); }
    if (i4 < n) { int p = atomicAdd(&cur[r4 >> 17], 1); lcols[p] = (int)(r4 & 0x1FFFF); }
    __syncthreads();

    // one quad per row: register accumulate, 8-wide unroll, 4 accumulators
    const int q = tid >> 2;          // 0..127
    const int lane = tid & 3;
    const int node = row0 + q;
    float4 acc = make_float4(0.f, 0.f, 0.f, 0.f);
    float4 acc2 = make_float4(0.f, 0.f, 0.f, 0.f);
    float4 acc3 = make_float4(0.f, 0.f, 0.f, 0.f);
    float4 acc4 = make_float4(0.f, 0.f, 0.f, 0.f);
    int e = rptr[q];
    const int e1 = rptr[q + 1];
    for (; e + 8 <= e1; e += 8) {
        int c0 = lcols[e],     c1 = lcols[e + 1], c2 = lcols[e + 2], c3 = lcols[e + 3];
        int c4 = lcols[e + 4], c5 = lcols[e + 5], c6 = lcols[e + 6], c7 = lcols[e + 7];
        uint2 v0 = src[(size_t)c0 * 4 + lane];
        uint2 v1 = src[(size_t)c1 * 4 + lane];
        uint2 v2 = src[(size_t)c2 * 4 + lane];
        uint2 v3 = src[(size_t)c3 * 4 + lane];
        uint2 v4 = src[(size_t)c4 * 4 + lane];
        uint2 v5 = src[(size_t)c5 * 4 + lane];
        uint2 v6 = src[(size_t)c6 * 4 + lane];
        uint2 v7 = src[(size_t)c7 * 4 + lane];
        acc_half4(acc, v0);
        acc_half4(acc2, v1);
        acc_half4(acc3, v2);
        acc_half4(acc4, v3);
        acc_half4(acc, v4);
        acc_half4(acc2, v5);
        acc_half4(acc3, v6);
        acc_half4(acc4, v7);
    }
    for (; e + 2 <= e1; e += 2) {
        int c0 = lcols[e], c1 = lcols[e + 1];
        uint2 v0 = src[(size_t)c0 * 4 + lane];
        uint2 v1 = src[(size_t)c1 * 4 + lane];
        acc_half4(acc, v0);
        acc_half4(acc2, v1);
    }
    if (e < e1) {
        uint2 v = src[(size_t)lcols[e] * 4 + lane];
        acc_half4(acc, v);
    }
    acc.x += acc2.x; acc.y += acc2.y; acc.z += acc2.z; acc.w += acc2.w;
    acc3.x += acc4.x; acc3.y += acc4.y; acc3.z += acc4.z; acc3.w += acc4.w;
    acc.x += acc3.x; acc.y += acc3.y; acc.z += acc3.z; acc.w += acc3.w;

    if (!POOL) {
        if (node < N) {
            __half2 h01 = __floats2half2_rn(acc.x, acc.y);
            __half2 h23 = __floats2half2_rn(acc.z, acc.w);
            uint2 pkd;
            pkd.x = *(unsigned int*)&h01;
            pkd.y = *(unsigned int*)&h23;
            dst[(size_t)node * 4 + lane] = pkd;
        }
    } else {
        int g_first = sbatch[0];
        if (node < N) {
            int g = sbatch[q];
            int idx = g - g_first;
            if (idx < 32) {
                float* sp = &spool[idx * PC + lane * 4];
                atomicAdd(sp + 0, acc.x);
                atomicAdd(sp + 1, acc.y);
                atomicAdd(sp + 2, acc.z);
                atomicAdd(sp + 3, acc.w);
                if (lane == 0) atomicAdd(&spcnt[idx], 1);
            } else {
                float* pp = pooled + (size_t)g * PC + lane * 4;
                unsafeAtomicAdd(pp + 0, acc.x);
                unsafeAtomicAdd(pp + 1, acc.y);
                unsafeAtomicAdd(pp + 2, acc.z);
                unsafeAtomicAdd(pp + 3, acc.w);
                if (lane == 0) atomicAdd(&gcount[g], 1);
            }
        }
        __syncthreads();
        int lastrl = min(row0 + 127, N - 1) - row0;
        int span = min(sbatch[lastrl] - g_first + 1, 32);
        for (int t = tid; t < span * PC; t += 512) {
            float v = spool[t];
            if (v != 0.f)
                unsafeAtomicAdd(&pooled[(size_t)(g_first + (t >> 4)) * PC + (t & 15)], v);
        }
        if (tid < span && spcnt[tid] > 0)
            atomicAdd(&gcount[g_first + tid], spcnt[tid]);
    }
}

// ---------- finalize: out[g,c] = pooled[g,c]/max(gcount[g],1) + b[c] ----------

__global__ void finalize(const float* __restrict__ pooled, const int* __restrict__ gcount,
                         const float* __restrict__ bvec, float* __restrict__ out) {
    int idx = blockIdx.x * blockDim.x + threadIdx.x;
    if (idx >= GG * CC) return;
    int g = idx / CC, c = idx % CC;
    int cg = gcount[g];
    out[idx] = pooled[g * PC + c] / (float)(cg > 0 ? cg : 1) + bvec[c];
}

// ---------- launch ----------

static inline size_t al256(size_t x) { return (x + 255) & ~(size_t)255; }

extern "C" void kernel_launch(void* const* d_in, const int* in_sizes, int n_in,
                              void* d_out, int out_size, void* d_ws, size_t ws_size,
                              hipStream_t stream) {
    const float* x    = (const float*)d_in[0];
    const int*   eidx = (const int*)d_in[1];   // [2][E]: row then col
    const int*   batch= (const int*)d_in[2];
    const float* W    = (const float*)d_in[3];
    const float* bvec = (const float*)d_in[4];
    float* out = (float*)d_out;

    char* p = (char*)d_ws;
    int*   wfill  = (int*)p;   p += al256((size_t)NW * 4);
    size_t zbytes = (size_t)(p - (char*)d_ws);      // only wfill needs memset
    float* pooled = (float*)p; p += al256((size_t)GG * PC * 4);
    int*   gcount = (int*)p;   p += al256((size_t)GG * 4);
    unsigned int* rec = (unsigned int*)p; p += al256((size_t)NW * WCAP * 4);
    uint2* y0     = (uint2*)p; p += al256((size_t)NW * 128 * 32);   // fp16 [N][16]
    uint2* y1     = (uint2*)p; p += al256((size_t)NW * 128 * 32);

    hipMemsetAsync(wfill, 0, zbytes, stream);

    prep<<<PB + XB, 1024, 0, stream>>>(eidx, wfill, rec,
                                       (const float4*)x, W, y0, pooled, gcount, EE, NN);

    window_spmm<false><<<NW, 512, 0, stream>>>(y0, rec, wfill, nullptr,
                                               y1, nullptr, nullptr, NN);

    window_spmm<true><<<NW, 512, 0, stream>>>(y1, rec, wfill, batch,
                                              nullptr, pooled, gcount, NN);

    finalize<<<(GG * CC + 255) / 256, 256, 0, stream>>>(pooled, gcount, bvec, out);
}